// Round 2
// baseline (521.387 us; speedup 1.0000x reference)
//
#include <hip/hip_runtime.h>
#include <math.h>

#define BB 4096
#define CC 32
#define TT 512
#define NOUTC 16
#define EPSF 1e-5f
#define XS 520   // bf16 row stride in shorts: 1040 B, 16B-aligned

// ws layout (floats): 0: scale1[32]  32: shift1[32]  64: scale2[32]  96: shift2[32]
// 128: hT[32][4096] (131072)   131200: part[64][4096] (262144)
// 393344: x2h bf16-pairs as u32 [4096][32][256]  (128 MB)  -> need ~129.5 MB total

typedef __attribute__((ext_vector_type(16))) float f32x16;
typedef __attribute__((ext_vector_type(4)))  float f32x4;
typedef __attribute__((ext_vector_type(8)))  short short8;
typedef __attribute__((ext_vector_type(4)))  unsigned int u32x4;
typedef __attribute__((ext_vector_type(4)))  float vf4;
typedef vf4 __attribute__((aligned(4))) vf4u;   // 4B-aligned float4 (dword-aligned dwordx4)

__device__ __forceinline__ unsigned short f2b(float f) {
  unsigned int u = __builtin_bit_cast(unsigned int, f);
  return (unsigned short)((u + 0x7FFFu + ((u >> 16) & 1u)) >> 16);
}
__device__ __forceinline__ float blo(unsigned int u) {
  return __builtin_bit_cast(float, u << 16);
}
__device__ __forceinline__ float bhi(unsigned int u) {
  return __builtin_bit_cast(float, u & 0xFFFF0000u);
}
// RN pack of 2 floats to bf16 pair (low = a, high = b)
__device__ __forceinline__ unsigned int pk2(float a, float b) {
  return (unsigned int)f2b(a) | ((unsigned int)f2b(b) << 16);
}

// depthwise conv for 2 consecutive t-columns per thread (t0 = tid*2), all 32 channels
__device__ __forceinline__ void conv_cols(const float* __restrict__ deb,
    const float* __restrict__ dw, const float* __restrict__ db_,
    int tid, float* x1A, float* x1B) {
  int t0 = tid * 2;
  int off = (tid == 0) ? 0 : ((tid == 255) ? t0 - 2 : t0 - 1);
#pragma unroll
  for (int c = 0; c < CC; c++) {
    vf4u v = *reinterpret_cast<const vf4u*>(deb + c * TT + off);
    float vm1 = (tid == 0) ? 0.f : ((tid == 255) ? v.y : v.x);
    float v0  = (tid == 0) ? v.x : ((tid == 255) ? v.z : v.y);
    float vp1 = (tid == 0) ? v.y : ((tid == 255) ? v.w : v.z);
    float vp2 = (tid == 0) ? v.z : ((tid == 255) ? 0.f : v.w);
    float w0 = dw[c * 3], w1 = dw[c * 3 + 1], w2 = dw[c * 3 + 2], bc = db_[c];
    x1A[c] = fmaf(w0, vm1, fmaf(w1, v0, fmaf(w2, vp1, bc)));
    x1B[c] = fmaf(w0, v0, fmaf(w1, vp1, fmaf(w2, vp2, bc)));
  }
}

// split one row (32 floats) into hi(trunc bf16)/lo(RN residual bf16) planes, write as 4x b128 each
__device__ __forceinline__ void stage_row(unsigned short* lds1, int XHo, int XLo,
                                          int row, const float* x) {
#pragma unroll
  for (int cb = 0; cb < 4; cb++) {
    u32x4 hv, lv;
#pragma unroll
    for (int k = 0; k < 4; k++) {
      float a = x[cb * 8 + 2 * k], b2 = x[cb * 8 + 2 * k + 1];
      unsigned int ua = __builtin_bit_cast(unsigned int, a);
      unsigned int ub = __builtin_bit_cast(unsigned int, b2);
      hv[k] = (ua >> 16) | (ub & 0xFFFF0000u);
      float ra = a - __builtin_bit_cast(float, ua & 0xFFFF0000u);
      float rb = b2 - __builtin_bit_cast(float, ub & 0xFFFF0000u);
      lv[k] = pk2(ra, rb);
    }
    *(u32x4*)&lds1[XHo + row * 40 + cb * 8] = hv;
    *(u32x4*)&lds1[XLo + row * 40 + cb * 8] = lv;
  }
}

// ---------------- kernel 1: conv -> MFMA pointwise (bf16 hi/lo split) -> x2h + BN1 partials ----
__global__ __launch_bounds__(256) void k1_stats(const float* __restrict__ de,
    const float* __restrict__ dw, const float* __restrict__ db_,
    const float* __restrict__ pw, const float* __restrict__ pwb,
    float* __restrict__ part, unsigned int* __restrict__ x2h, int useWs) {
  // LDS layout (shorts): XH[256][40], XL[256][40], X2B[32][520], PWH[32][32], PWL[32][32]
  // = 10240 + 10240 + 16640 + 1024 + 1024 = 39168 shorts = 78336 B -> 2 blocks/CU
  __shared__ __align__(16) unsigned short lds1[39168];
  const int XHo = 0, XLo = 10240, X2Bo = 20480, PWHo = 37120, PWLo = 38144;

  int tid = threadIdx.x, b = blockIdx.x;
  int lane = tid & 63, w = tid >> 6;
  int m31 = lane & 31, kh = lane >> 5;

  const float* deb = de + (size_t)b * CC * TT;
  float x1A[CC], x1B[CC];
  conv_cols(deb, dw, db_, tid, x1A, x1B);

  // stage pw hi/lo (A operand), [o][c] row-major, stride 32 shorts
  for (int i = tid; i < CC * CC; i += 256) {
    float v = pw[i];
    unsigned int u = __builtin_bit_cast(unsigned int, v);
    lds1[PWHo + i] = (unsigned short)(u >> 16);
    float r = v - __builtin_bit_cast(float, u & 0xFFFF0000u);
    lds1[PWLo + i] = f2b(r);
  }
  __syncthreads();

  // A-frags (reused for every tile): lane m31 reads pw[m31][s*16 + kh*8 .. +7]
  short8 ah[2], al[2];
#pragma unroll
  for (int s = 0; s < 2; s++) {
    ah[s] = *(const short8*)&lds1[PWHo + m31 * 32 + s * 16 + kh * 8];
    al[s] = *(const short8*)&lds1[PWLo + m31 * 32 + s * 16 + kh * 8];
  }
  // per-reg output-channel bias
  float pbv[16];
#pragma unroll
  for (int r = 0; r < 16; r++) pbv[r] = pwb[(r & 3) + 8 * (r >> 2) + 4 * kh];

#pragma unroll
  for (int h = 0; h < 2; h++) {
    // stage this half of x1^T ([t][c] layout, hi/lo planes) from registers
    if ((tid >> 7) == h) {
      int lr = 2 * (tid & 127);
      stage_row(lds1, XHo, XLo, lr, x1A);
      stage_row(lds1, XHo, XLo, lr + 1, x1B);
    }
    __syncthreads();

    // 8 t-tiles in this half, 2 per wave; D[o][t] = sum_c pw[o][c] * x1[c][t]
#pragma unroll
    for (int i = 0; i < 2; i++) {
      int wt = w * 2 + i;
      f32x16 acc;
#pragma unroll
      for (int r = 0; r < 16; r++) acc[r] = 0.f;
      int rowb = wt * 32 + m31;
#pragma unroll
      for (int s = 0; s < 2; s++) {
        short8 bh = *(const short8*)&lds1[XHo + rowb * 40 + s * 16 + kh * 8];
        short8 bl = *(const short8*)&lds1[XLo + rowb * 40 + s * 16 + kh * 8];
        acc = __builtin_amdgcn_mfma_f32_32x32x16_bf16(ah[s], bh, acc, 0, 0, 0);
        acc = __builtin_amdgcn_mfma_f32_32x32x16_bf16(ah[s], bl, acc, 0, 0, 0);
        acc = __builtin_amdgcn_mfma_f32_32x32x16_bf16(al[s], bh, acc, 0, 0, 0);
      }
      // epilogue: +bias, RN->bf16, bounce to LDS [o][t] (regs r,r+1 are o,o+1)
      int t = h * 256 + wt * 32 + m31;
#pragma unroll
      for (int pr = 0; pr < 8; pr++) {
        int o0 = ((2 * pr) & 3) + 8 * (pr >> 1) + 4 * kh;
        unsigned int p = pk2(acc[2 * pr] + pbv[2 * pr], acc[2 * pr + 1] + pbv[2 * pr + 1]);
        lds1[X2Bo + o0 * 520 + t] = (unsigned short)(p & 0xFFFFu);
        lds1[X2Bo + (o0 + 1) * 520 + t] = (unsigned short)(p >> 16);
      }
    }
    __syncthreads();   // xh/xl reads done before h=1 restage; x2b complete before copy
  }

  // fused coalesced x2h write + BN1 stat partials (s, q per channel)
  unsigned int* xw = x2h + (size_t)b * (CC * 256);
  int L = tid & 63;
#pragma unroll
  for (int it = 0; it < 8; it++) {
    int o = it * 4 + w;
    u32x4 v = *(const u32x4*)&lds1[X2Bo + o * 520 + L * 8];
    float s = 0.f, q = 0.f;
#pragma unroll
    for (int k = 0; k < 4; k++) {
      float a = blo(v[k]), c2 = bhi(v[k]);
      s += a + c2;
      q = fmaf(a, a, fmaf(c2, c2, q));
    }
#pragma unroll
    for (int d = 1; d < 64; d <<= 1) { s += __shfl_xor(s, d); q += __shfl_xor(q, d); }
    if (L == 0) {
      part[(size_t)o * BB + b] = s;
      part[(size_t)(32 + o) * BB + b] = q;
    }
    if (useWs) *(u32x4*)(xw + (size_t)(it * 256 + tid) * 4) = v;
  }
}

// ---------------- kernel 2: finalize BN1 scale/shift ----------------
__global__ void k2_bn1(const float* __restrict__ part, const float* __restrict__ g,
                       const float* __restrict__ bta, float* __restrict__ ws) {
  __shared__ float redS[256], redQ[256];
  int o = blockIdx.x, tid = threadIdx.x;
  const float* ps = part + (size_t)o * BB;
  const float* pq = part + (size_t)(CC + o) * BB;
  float s = 0, q = 0;
  for (int i = tid; i < BB; i += 256) { s += ps[i]; q += pq[i]; }
  redS[tid] = s; redQ[tid] = q;
  __syncthreads();
  for (int k = 128; k > 0; k >>= 1) {
    if (tid < k) { redS[tid] += redS[tid + k]; redQ[tid] += redQ[tid + k]; }
    __syncthreads();
  }
  if (tid == 0) {
    float N = (float)BB * (float)TT;
    float mean = redS[0] / N;
    float var = redQ[0] / N - mean * mean;
    float sc = g[o] / sqrtf(var + EPSF);
    ws[o] = sc;
    ws[32 + o] = bta[o] - mean * sc;
  }
}

// ---------------- kernel 3: per-sample main pipeline (MFMA Gram + Z) ----------------
__global__ __launch_bounds__(256) void k3_main(const float* __restrict__ de,
    const float* __restrict__ dw, const float* __restrict__ db_,
    const float* __restrict__ pw, const float* __restrict__ pwb,
    const float* __restrict__ ws, const float* __restrict__ gcw,
    const float* __restrict__ fcw, const float* __restrict__ fcb,
    float* __restrict__ hT, const unsigned int* __restrict__ x2h, int useWs) {
  __shared__ __align__(16) unsigned short x_s[CC * XS];
  __shared__ __align__(16) unsigned short gc_s[NOUTC * XS];
  __shared__ float gramP[2][CC * CC];
  __shared__ float zP[2][CC * NOUTC];
  __shared__ float num_s[CC * 33];
  __shared__ float red16[CC * 8];
  __shared__ float mu_s[CC], inv_s[CC];
  __shared__ float Zi_s[CC * NOUTC];
  __shared__ float g2_s[CC * NOUTC];
  __shared__ float red2[CC * 9];

  int tid = threadIdx.x, b = blockIdx.x;
  int w = tid >> 6, lane = tid & 63;
  int t0 = tid * 2;

  // stage gc_w^T as bf16 (gcw is [512][16] row-major)
  for (int i = tid; i < TT * NOUTC; i += 256) {
    int t = i >> 4, o = i & 15;
    gc_s[o * XS + t] = f2b(gcw[i]);
  }

  if (useWs) {
    // load pre-BN bf16 x2, apply BN1 + relu, round, store to LDS
    const unsigned int* xr = x2h + (size_t)b * CC * 256;
#pragma unroll
    for (int o = 0; o < CC; o++) {
      unsigned int u = xr[o * 256 + tid];
      float sc = ws[o], sh = ws[32 + o];
      unsigned short hA = f2b(fmaxf(fmaf(blo(u), sc, sh), 0.f));
      unsigned short hB = f2b(fmaxf(fmaf(bhi(u), sc, sh), 0.f));
      *(unsigned int*)(&x_s[o * XS + t0]) = (unsigned int)hA | ((unsigned int)hB << 16);
    }
  } else {
    // fallback: recompute conv
    const float* deb = de + (size_t)b * CC * TT;
    float x1A[CC], x1B[CC];
    conv_cols(deb, dw, db_, tid, x1A, x1B);
#pragma unroll
    for (int o = 0; o < CC; o++) {
      float aA = pwb[o], aB = pwb[o];
#pragma unroll
      for (int c = 0; c < CC; c++) { float pv = pw[o * CC + c]; aA = fmaf(pv, x1A[c], aA); aB = fmaf(pv, x1B[c], aB); }
      float sc = ws[o], sh = ws[32 + o];
      unsigned short hA = f2b(fmaxf(fmaf(aA, sc, sh), 0.f));
      unsigned short hB = f2b(fmaxf(fmaf(aB, sc, sh), 0.f));
      *(unsigned int*)(&x_s[o * XS + t0]) = (unsigned int)hA | ((unsigned int)hB << 16);
    }
  }
  __syncthreads();

  // mu partials: strided LDS re-read of x_s (c = tid>>3 row, j = tid&7 chunk of 64 t)
  {
    int c = tid >> 3, j = tid & 7;
    float s = 0.f;
#pragma unroll
    for (int it = 0; it < 8; it++) {
      u32x4 u = *reinterpret_cast<const u32x4*>(&x_s[c * XS + j * 64 + it * 8]);
#pragma unroll
      for (int k = 0; k < 4; k++) s += blo(u[k]) + bhi(u[k]);
    }
    red16[c * 8 + j] = s;
  }

  // MFMA: waves 0,1 = Gram halves (32x32x16, A-frag == B-frag); waves 2,3 = Z halves (16x16x32)
  if (w < 2) {
    int m = lane & 31, kh = lane >> 5;
    f32x16 acc;
#pragma unroll
    for (int r = 0; r < 16; r++) acc[r] = 0.f;
    int kbase = w * 256 + kh * 8;
#pragma unroll
    for (int kk = 0; kk < 256; kk += 16) {
      short8 a = *(const short8*)(&x_s[m * XS + kbase + kk]);
      acc = __builtin_amdgcn_mfma_f32_32x32x16_bf16(a, a, acc, 0, 0, 0);
    }
#pragma unroll
    for (int r = 0; r < 16; r++) {
      int row = (r & 3) + 8 * (r >> 2) + 4 * kh;   // C/D: col=lane&31, row per m74/m101
      gramP[w][row * CC + m] = acc[r];
    }
  } else {
    int w2 = w - 2;
    int n16 = lane & 15, q = lane >> 4;
    f32x4 ac0, ac1;
#pragma unroll
    for (int r = 0; r < 4; r++) { ac0[r] = 0.f; ac1[r] = 0.f; }
    int kbase = w2 * 256 + q * 8;
#pragma unroll
    for (int kk = 0; kk < 256; kk += 32) {
      short8 bfr = *(const short8*)(&gc_s[n16 * XS + kbase + kk]);
      short8 af0 = *(const short8*)(&x_s[n16 * XS + kbase + kk]);
      short8 af1 = *(const short8*)(&x_s[(16 + n16) * XS + kbase + kk]);
      ac0 = __builtin_amdgcn_mfma_f32_16x16x32_bf16(af0, bfr, ac0, 0, 0, 0);
      ac1 = __builtin_amdgcn_mfma_f32_16x16x32_bf16(af1, bfr, ac1, 0, 0, 0);
    }
#pragma unroll
    for (int r = 0; r < 4; r++) {
      int row = q * 4 + r;
      zP[w2][row * NOUTC + n16] = ac0[r];
      zP[w2][(16 + row) * NOUTC + n16] = ac1[r];
    }
  }
  __syncthreads();
  if (tid < CC) {
    float s = 0.f;
#pragma unroll
    for (int j = 0; j < 8; j++) s += red16[tid * 8 + j];
    mu_s[tid] = s;   // Sx per channel
  }
  __syncthreads();
  // centered Gram: num_c = Sxx - Sx_n*Sx_m/T   (cor = num_c / sqrt(diag_n diag_m))
  for (int i = tid; i < CC * CC; i += 256) {
    int n = i >> 5, m = i & 31;
    num_s[n * 33 + m] = gramP[0][i] + gramP[1][i] - mu_s[n] * mu_s[m] * (1.f / (float)TT);
  }
  for (int i = tid; i < CC * NOUTC; i += 256) Zi_s[i] = zP[0][i] + zP[1][i];
  __syncthreads();
  if (tid < CC) inv_s[tid] = rsqrtf(num_s[tid * 33 + tid]);
  __syncthreads();
  // g2[n][o] = relu(inv_n * sum_m num_c[n][m] * inv_m * Z[m][o])
  for (int i = tid; i < CC * NOUTC; i += 256) {
    int n = i >> 4, o = i & 15;
    float s = 0.f;
#pragma unroll
    for (int m = 0; m < CC; m++) s = fmaf(num_s[n * 33 + m] * inv_s[m], Zi_s[m * NOUTC + o], s);
    g2_s[i] = fmaxf(s * inv_s[n], 0.f);
  }
  __syncthreads();
  // fc: h[j] = fcb[j] + sum_i g2[i] * fcw[i][j]
  {
    int j = tid & 31, ch = tid >> 5;
    float p = 0.f;
#pragma unroll
    for (int ii = 0; ii < 64; ii++) {
      int i = ch * 64 + ii;
      p = fmaf(g2_s[i], fcw[i * CC + j], p);
    }
    red2[j * 9 + ch] = p;
  }
  __syncthreads();
  if (tid < CC) {
    float h = fcb[tid];
#pragma unroll
    for (int ch = 0; ch < 8; ch++) h += red2[tid * 9 + ch];
    hT[(size_t)tid * BB + b] = h;
  }
}

// ---------------- kernel 4: BN2 stats ----------------
__global__ void k4_bn2(const float* __restrict__ hT, const float* __restrict__ g,
                       const float* __restrict__ bta, float* __restrict__ ws) {
  __shared__ float redS[256], redQ[256];
  int j = blockIdx.x, tid = threadIdx.x;
  const float* row = hT + (size_t)j * BB;
  float s = 0, q = 0;
  for (int i = tid; i < BB; i += 256) { float v = row[i]; s += v; q = fmaf(v, v, q); }
  redS[tid] = s; redQ[tid] = q;
  __syncthreads();
  for (int k = 128; k > 0; k >>= 1) {
    if (tid < k) { redS[tid] += redS[tid + k]; redQ[tid] += redQ[tid + k]; }
    __syncthreads();
  }
  if (tid == 0) {
    float N = (float)BB;
    float mean = redS[0] / N;
    float var = redQ[0] / N - mean * mean;
    float sc = g[j] / sqrtf(var + EPSF);
    ws[64 + j] = sc;
    ws[96 + j] = bta[j] - mean * sc;
  }
}

// ---------------- kernel 5: BN2 apply + sigmoid + classifier ----------------
__global__ void k5_out(const float* __restrict__ hT, const float* __restrict__ ws,
                       const float* __restrict__ clsw, const float* __restrict__ clsb,
                       float* __restrict__ out) {
  __shared__ float hs[CC * 257];
  int b0 = blockIdx.x * 256, tid = threadIdx.x;
  for (int i = tid; i < CC * 256; i += 256) {
    int j = i >> 8, bb = i & 255;
    float v = fmaf(hT[(size_t)j * BB + b0 + bb], ws[64 + j], ws[96 + j]);
    hs[j * 257 + bb] = 1.f / (1.f + expf(-v));
  }
  __syncthreads();
  float o0 = clsb[0], o1 = clsb[1], o2 = clsb[2], o3 = clsb[3];
#pragma unroll
  for (int j = 0; j < CC; j++) {
    float h = hs[j * 257 + tid];
    o0 = fmaf(h, clsw[j * 4 + 0], o0);
    o1 = fmaf(h, clsw[j * 4 + 1], o1);
    o2 = fmaf(h, clsw[j * 4 + 2], o2);
    o3 = fmaf(h, clsw[j * 4 + 3], o3);
  }
  float4* out4 = reinterpret_cast<float4*>(out);
  out4[b0 + tid] = make_float4(o0, o1, o2, o3);
}

extern "C" void kernel_launch(void* const* d_in, const int* in_sizes, int n_in,
                              void* d_out, int out_size, void* d_ws, size_t ws_size,
                              hipStream_t stream) {
  const float* de   = (const float*)d_in[0];
  const float* dw   = (const float*)d_in[2];
  const float* db_  = (const float*)d_in[3];
  const float* pw   = (const float*)d_in[4];
  const float* pwb  = (const float*)d_in[5];
  const float* bn1g = (const float*)d_in[6];
  const float* bn1b = (const float*)d_in[7];
  const float* gcw  = (const float*)d_in[8];
  const float* fcw  = (const float*)d_in[9];
  const float* fcb  = (const float*)d_in[10];
  const float* bn2g = (const float*)d_in[11];
  const float* bn2b = (const float*)d_in[12];
  const float* clsw = (const float*)d_in[13];
  const float* clsb = (const float*)d_in[14];

  float* ws   = (float*)d_ws;
  float* hT   = ws + 128;
  float* part = ws + 131200;
  unsigned int* x2h = (unsigned int*)(ws + 393344);
  float* out  = (float*)d_out;

  size_t need = 393344ull * 4ull + (size_t)BB * CC * 256 * 4;  // ~129.5 MB
  int useWs = (ws_size >= need) ? 1 : 0;

  k1_stats<<<BB, 256, 0, stream>>>(de, dw, db_, pw, pwb, part, x2h, useWs);
  k2_bn1<<<CC, 256, 0, stream>>>(part, bn1g, bn1b, ws);
  k3_main<<<BB, 256, 0, stream>>>(de, dw, db_, pw, pwb, ws, gcw, fcw, fcb, hT, x2h, useWs);
  k4_bn2<<<CC, 256, 0, stream>>>(hT, bn2g, bn2b, ws);
  k5_out<<<BB / 256, 256, 0, stream>>>(hT, ws, clsw, clsb, out);
}

// Round 3
// 486.998 us; speedup vs baseline: 1.0706x; 1.0706x over previous
//
#include <hip/hip_runtime.h>
#include <math.h>

#define BB 4096
#define CC 32
#define TT 512
#define NOUTC 16
#define EPSF 1e-5f
#define XS 520   // bf16 row stride in shorts for k3 x_s: 1040 B, 16B-aligned

// ws layout (floats):
// 0: scale1[32]  32: shift1[32]  64: scale2[32]  96: shift2[32]
// 128: gcf bf16 frags u16[8192] (4096 floats)
// 4224: hT[32][4096] (131072)
// 135296: part[64][4096] (262144)
// 397440: x2h bf16-pairs as u32 [4096][2 half][32 o][128 tp] (128 MB)

typedef __attribute__((ext_vector_type(16))) float f32x16;
typedef __attribute__((ext_vector_type(4)))  float f32x4;
typedef __attribute__((ext_vector_type(8)))  short short8;
typedef __attribute__((ext_vector_type(8)))  _Float16 half8;
typedef __attribute__((ext_vector_type(4)))  unsigned int u32x4;
typedef __attribute__((ext_vector_type(4)))  float vf4;
typedef vf4 __attribute__((aligned(4))) vf4u;   // 4B-aligned float4 (dword-aligned dwordx4)

__device__ __forceinline__ unsigned short f2b(float f) {
  unsigned int u = __builtin_bit_cast(unsigned int, f);
  return (unsigned short)((u + 0x7FFFu + ((u >> 16) & 1u)) >> 16);
}
__device__ __forceinline__ float blo(unsigned int u) {
  return __builtin_bit_cast(float, u << 16);
}
__device__ __forceinline__ float bhi(unsigned int u) {
  return __builtin_bit_cast(float, u & 0xFFFF0000u);
}
// RN pack of 2 floats to bf16 pair (low = a, high = b)
__device__ __forceinline__ unsigned int pk2(float a, float b) {
  return (unsigned int)f2b(a) | ((unsigned int)f2b(b) << 16);
}
__device__ __forceinline__ unsigned short h16(float f) {
  _Float16 h = (_Float16)f;
  return __builtin_bit_cast(unsigned short, h);
}
__device__ __forceinline__ unsigned int h2pk(float a, float b) {
  return (unsigned int)h16(a) | ((unsigned int)h16(b) << 16);
}

// depthwise conv for 2 consecutive t-columns per thread (t0 = tid*2), all 32 channels
__device__ __forceinline__ void conv_cols(const float* __restrict__ deb,
    const float* __restrict__ dw, const float* __restrict__ db_,
    int tid, float* x1A, float* x1B) {
  int t0 = tid * 2;
  int off = (tid == 0) ? 0 : ((tid == 255) ? t0 - 2 : t0 - 1);
#pragma unroll
  for (int c = 0; c < CC; c++) {
    vf4u v = *reinterpret_cast<const vf4u*>(deb + c * TT + off);
    float vm1 = (tid == 0) ? 0.f : ((tid == 255) ? v.y : v.x);
    float v0  = (tid == 0) ? v.x : ((tid == 255) ? v.z : v.y);
    float vp1 = (tid == 0) ? v.y : ((tid == 255) ? v.w : v.z);
    float vp2 = (tid == 0) ? v.z : ((tid == 255) ? 0.f : v.w);
    float w0 = dw[c * 3], w1 = dw[c * 3 + 1], w2 = dw[c * 3 + 2], bc = db_[c];
    x1A[c] = fmaf(w0, vm1, fmaf(w1, v0, fmaf(w2, vp1, bc)));
    x1B[c] = fmaf(w0, v0, fmaf(w1, vp1, fmaf(w2, vp2, bc)));
  }
}

// write one x1 row (32 floats) as fp16 into XF[row][40]
__device__ __forceinline__ void stage_row_f16(unsigned short* lds1, int row, const float* x) {
#pragma unroll
  for (int cb = 0; cb < 4; cb++) {
    u32x4 v;
#pragma unroll
    for (int k = 0; k < 4; k++) v[k] = h2pk(x[cb * 8 + 2 * k], x[cb * 8 + 2 * k + 1]);
    *(u32x4*)&lds1[row * 40 + cb * 8] = v;
  }
}

// ---------------- kernel 1: conv -> fp16 MFMA pointwise -> x2h + BN1 partials ----------------
__global__ __launch_bounds__(256, 3) void k1_stats(const float* __restrict__ de,
    const float* __restrict__ dw, const float* __restrict__ db_,
    const float* __restrict__ pw, const float* __restrict__ pwb,
    float* __restrict__ part, unsigned int* __restrict__ x2h, int useWs) {
  // LDS (shorts): XF[256][40] @0 (10240), X2B u16[32][264] @10240 (8448), PWF[32][32] @18688 (1024)
  // total 19712 shorts = 39424 B -> LDS allows 4 blocks/CU
  __shared__ __align__(16) unsigned short lds1[19712];
  const int XFo = 0, X2Bo = 10240, PWFo = 18688;

  int tid = threadIdx.x, b = blockIdx.x;
  int lane = tid & 63, w = tid >> 6;
  int m31 = lane & 31, kh = lane >> 5;
  int hw = tid >> 5, l32 = tid & 31;

  const float* deb = de + (size_t)b * CC * TT;
  float x1A[CC], x1B[CC];
  conv_cols(deb, dw, db_, tid, x1A, x1B);

  // stage pw as fp16, [o][c] row-major
  for (int i = tid; i < CC * CC; i += 256) lds1[PWFo + i] = h16(pw[i]);
  __syncthreads();

  // A-frags: lane m31 holds pw[o=m31][k-slice]
  half8 ah[2];
#pragma unroll
  for (int s = 0; s < 2; s++)
    ah[s] = *(const half8*)&lds1[PWFo + m31 * 32 + s * 16 + kh * 8];
  float pbv[16];
#pragma unroll
  for (int r = 0; r < 16; r++) pbv[r] = pwb[(r & 3) + 8 * (r >> 2) + 4 * kh];

  unsigned int* xw = x2h + (size_t)b * (CC * 256);
  float sAcc[4] = {0.f, 0.f, 0.f, 0.f}, qAcc[4] = {0.f, 0.f, 0.f, 0.f};

#pragma unroll
  for (int h = 0; h < 2; h++) {
    // stage this half of x1^T ([t][c], fp16) from registers
    if ((tid >> 7) == h) {
      int lr = 2 * (tid & 127);
      stage_row_f16(lds1, lr, x1A);
      stage_row_f16(lds1, lr + 1, x1B);
    }
    __syncthreads();   // XF ready; also: prior drain done before X2B overwritten

    // 8 t-tiles in this half, 2 per wave; D[o][t] = sum_c pw[o][c] * x1[c][t]
#pragma unroll
    for (int i = 0; i < 2; i++) {
      int wt = w * 2 + i;
      f32x16 acc;
#pragma unroll
      for (int r = 0; r < 16; r++) acc[r] = 0.f;
      int rowb = wt * 32 + m31;
#pragma unroll
      for (int s = 0; s < 2; s++) {
        half8 bh = *(const half8*)&lds1[XFo + rowb * 40 + s * 16 + kh * 8];
        acc = __builtin_amdgcn_mfma_f32_32x32x16_f16(ah[s], bh, acc, 0, 0, 0);
      }
      // epilogue: +bias, RN->bf16, bounce to X2B[o][tloc] (regs r,r+1 are o,o+1)
      int tloc = wt * 32 + m31;
#pragma unroll
      for (int pr = 0; pr < 8; pr++) {
        int o0 = ((2 * pr) & 3) + 8 * (pr >> 1) + 4 * kh;
        unsigned int p = pk2(acc[2 * pr] + pbv[2 * pr], acc[2 * pr + 1] + pbv[2 * pr + 1]);
        lds1[X2Bo + o0 * 264 + tloc] = (unsigned short)(p & 0xFFFFu);
        lds1[X2Bo + (o0 + 1) * 264 + tloc] = (unsigned short)(p >> 16);
      }
    }
    __syncthreads();   // X2B complete

    // fused coalesced x2h write + BN1 stat partials for this half
#pragma unroll
    for (int it = 0; it < 4; it++) {
      int o = it * 8 + hw;
      u32x4 v = *(const u32x4*)&lds1[X2Bo + o * 264 + l32 * 8];
      float s = 0.f, q = 0.f;
#pragma unroll
      for (int k = 0; k < 4; k++) {
        float a = blo(v[k]), c2 = bhi(v[k]);
        s += a + c2;
        q = fmaf(a, a, fmaf(c2, c2, q));
      }
#pragma unroll
      for (int d = 1; d < 32; d <<= 1) { s += __shfl_xor(s, d); q += __shfl_xor(q, d); }
      sAcc[it] += s; qAcc[it] += q;
      if (useWs) *(u32x4*)(xw + (size_t)h * 4096 + o * 128 + l32 * 4) = v;
    }
  }

  if (l32 == 0) {
#pragma unroll
    for (int it = 0; it < 4; it++) {
      int o = it * 8 + hw;
      part[(size_t)o * BB + b] = sAcc[it];
      part[(size_t)(32 + o) * BB + b] = qAcc[it];
    }
  }
}

// ---------------- kernel 2: finalize BN1 scale/shift + gc fragment precompute ----------------
__global__ void k2_bn1(const float* __restrict__ part, const float* __restrict__ g,
                       const float* __restrict__ bta, float* __restrict__ ws,
                       const float* __restrict__ gcw, unsigned short* __restrict__ gcf) {
  __shared__ float redS[256], redQ[256];
  int o = blockIdx.x, tid = threadIdx.x;
  // gc fragment precompute: gcf[((w2*8+j)*64 + lane)*8 + e] = bf16(gcw[t*16 + n16])
  {
    int i = o * 256 + tid;              // 0..8191
    int e = i & 7, ln = (i >> 3) & 63, j = (i >> 9) & 7, w2 = i >> 12;
    int q = ln >> 4, n16 = ln & 15;
    int t = w2 * 256 + q * 8 + j * 32 + e;
    gcf[i] = f2b(gcw[t * 16 + n16]);
  }
  const float* ps = part + (size_t)o * BB;
  const float* pq = part + (size_t)(CC + o) * BB;
  float s = 0, q = 0;
  for (int i = tid; i < BB; i += 256) { s += ps[i]; q += pq[i]; }
  redS[tid] = s; redQ[tid] = q;
  __syncthreads();
  for (int k = 128; k > 0; k >>= 1) {
    if (tid < k) { redS[tid] += redS[tid + k]; redQ[tid] += redQ[tid + k]; }
    __syncthreads();
  }
  if (tid == 0) {
    float N = (float)BB * (float)TT;
    float mean = redS[0] / N;
    float var = redQ[0] / N - mean * mean;
    float sc = g[o] / sqrtf(var + EPSF);
    ws[o] = sc;
    ws[32 + o] = bta[o] - mean * sc;
  }
}

// ---------------- kernel 3: per-sample main pipeline (MFMA Gram + Z) ----------------
__global__ __launch_bounds__(256, 3) void k3_main(const float* __restrict__ de,
    const float* __restrict__ dw, const float* __restrict__ db_,
    const float* __restrict__ pw, const float* __restrict__ pwb,
    const float* __restrict__ ws, const unsigned short* __restrict__ gcf,
    const float* __restrict__ fcw, const float* __restrict__ fcb,
    float* __restrict__ hT, const unsigned int* __restrict__ x2h, int useWs) {
  __shared__ __align__(16) unsigned short x_s[CC * XS];   // 33280 B
  __shared__ float gramP[2][CC * CC];                     // 8192 B; [0] reused as num, [1] as red2
  __shared__ float zP[2][CC * NOUTC];                     // 4096 B; [0] reused as Zi, [1] as g2
  __shared__ float red16[CC * 8];                         // 1024 B
  __shared__ float mu_s[CC], inv_s[CC];                   // 256 B
  // total ~46.8 KB -> 3 blocks/CU

  int tid = threadIdx.x, b = blockIdx.x;
  int w = tid >> 6, lane = tid & 63;
  int t0 = tid * 2;

  if (useWs) {
    // load pre-BN bf16 x2 ([h][o][tp] layout), apply BN1 + relu, round, store to LDS
    const unsigned int* xr = x2h + (size_t)b * (CC * 256);
    int base = (tid >> 7) * 4096 + (tid & 127);
#pragma unroll
    for (int o = 0; o < CC; o++) {
      unsigned int u = xr[base + o * 128];
      float sc = ws[o], sh = ws[32 + o];
      unsigned short hA = f2b(fmaxf(fmaf(blo(u), sc, sh), 0.f));
      unsigned short hB = f2b(fmaxf(fmaf(bhi(u), sc, sh), 0.f));
      *(unsigned int*)(&x_s[o * XS + t0]) = (unsigned int)hA | ((unsigned int)hB << 16);
    }
  } else {
    // fallback: recompute conv + pointwise (scalar)
    const float* deb = de + (size_t)b * CC * TT;
    float x1A[CC], x1B[CC];
    conv_cols(deb, dw, db_, tid, x1A, x1B);
#pragma unroll
    for (int o = 0; o < CC; o++) {
      float aA = pwb[o], aB = pwb[o];
#pragma unroll
      for (int c = 0; c < CC; c++) { float pv = pw[o * CC + c]; aA = fmaf(pv, x1A[c], aA); aB = fmaf(pv, x1B[c], aB); }
      float sc = ws[o], sh = ws[32 + o];
      unsigned short hA = f2b(fmaxf(fmaf(aA, sc, sh), 0.f));
      unsigned short hB = f2b(fmaxf(fmaf(aB, sc, sh), 0.f));
      *(unsigned int*)(&x_s[o * XS + t0]) = (unsigned int)hA | ((unsigned int)hB << 16);
    }
  }
  __syncthreads();

  // mu partials: strided LDS re-read of x_s
  {
    int c = tid >> 3, j = tid & 7;
    float s = 0.f;
#pragma unroll
    for (int it = 0; it < 8; it++) {
      u32x4 u = *reinterpret_cast<const u32x4*>(&x_s[c * XS + j * 64 + it * 8]);
#pragma unroll
      for (int k = 0; k < 4; k++) s += blo(u[k]) + bhi(u[k]);
    }
    red16[c * 8 + j] = s;
  }

  // MFMA: waves 0,1 = Gram halves (32x32x16); waves 2,3 = Z halves (16x16x32, gc frags from L2)
  if (w < 2) {
    int m = lane & 31, kh = lane >> 5;
    f32x16 acc;
#pragma unroll
    for (int r = 0; r < 16; r++) acc[r] = 0.f;
    int kbase = w * 256 + kh * 8;
#pragma unroll
    for (int kk = 0; kk < 256; kk += 16) {
      short8 a = *(const short8*)(&x_s[m * XS + kbase + kk]);
      acc = __builtin_amdgcn_mfma_f32_32x32x16_bf16(a, a, acc, 0, 0, 0);
    }
#pragma unroll
    for (int r = 0; r < 16; r++) {
      int row = (r & 3) + 8 * (r >> 2) + 4 * kh;   // C/D: col=lane&31, row per m74/m101
      gramP[w][row * CC + m] = acc[r];
    }
  } else {
    int w2 = w - 2;
    int n16 = lane & 15, q = lane >> 4;
    f32x4 ac0, ac1;
#pragma unroll
    for (int r = 0; r < 4; r++) { ac0[r] = 0.f; ac1[r] = 0.f; }
    const unsigned short* gf = gcf + w2 * 4096;
    short8 bfr[8];
#pragma unroll
    for (int j = 0; j < 8; j++) bfr[j] = *(const short8*)(gf + (j * 64 + lane) * 8);
    int kbase = w2 * 256 + q * 8;
#pragma unroll
    for (int j = 0; j < 8; j++) {
      int kk = j * 32;
      short8 af0 = *(const short8*)(&x_s[n16 * XS + kbase + kk]);
      short8 af1 = *(const short8*)(&x_s[(16 + n16) * XS + kbase + kk]);
      ac0 = __builtin_amdgcn_mfma_f32_16x16x32_bf16(af0, bfr[j], ac0, 0, 0, 0);
      ac1 = __builtin_amdgcn_mfma_f32_16x16x32_bf16(af1, bfr[j], ac1, 0, 0, 0);
    }
#pragma unroll
    for (int r = 0; r < 4; r++) {
      int row = q * 4 + r;
      zP[w2][row * NOUTC + n16] = ac0[r];
      zP[w2][(16 + row) * NOUTC + n16] = ac1[r];
    }
  }
  __syncthreads();
  if (tid < CC) {
    float s = 0.f;
#pragma unroll
    for (int j = 0; j < 8; j++) s += red16[tid * 8 + j];
    mu_s[tid] = s;   // Sx per channel
  }
  __syncthreads();
  // num (into gramP[0], stride 32): num = Sxx - Sx_n*Sx_m/T ; Zi (into zP[0])
  float* gram0 = gramP[0];
  float* Zi = zP[0];
  float* g2 = zP[1];
  for (int i = tid; i < CC * CC; i += 256) {
    int n = i >> 5, m = i & 31;
    gram0[i] = gram0[i] + gramP[1][i] - mu_s[n] * mu_s[m] * (1.f / (float)TT);
  }
  for (int i = tid; i < CC * NOUTC; i += 256) Zi[i] = zP[0][i] + zP[1][i];
  __syncthreads();
  if (tid < CC) inv_s[tid] = rsqrtf(gram0[tid * 32 + tid]);
  __syncthreads();
  // g2[n][o] = relu(inv_n * sum_m num[n][m] * inv_m * Zi[m][o])  (into zP[1])
  for (int i = tid; i < CC * NOUTC; i += 256) {
    int n = i >> 4, o = i & 15;
    float s = 0.f;
#pragma unroll
    for (int m = 0; m < CC; m++) s = fmaf(gram0[n * 32 + m] * inv_s[m], Zi[m * NOUTC + o], s);
    g2[i] = fmaxf(s * inv_s[n], 0.f);
  }
  __syncthreads();
  // fc: h[j] = fcb[j] + sum_i g2[i] * fcw[i][j]   (partials into red2 = gramP[1])
  float* red2 = gramP[1];
  {
    int j = tid & 31, ch = tid >> 5;
    float p = 0.f;
#pragma unroll
    for (int ii = 0; ii < 64; ii++) {
      int i = ch * 64 + ii;
      p = fmaf(g2[i], fcw[i * CC + j], p);
    }
    red2[j * 9 + ch] = p;
  }
  __syncthreads();
  if (tid < CC) {
    float h = fcb[tid];
#pragma unroll
    for (int ch = 0; ch < 8; ch++) h += red2[tid * 9 + ch];
    hT[(size_t)tid * BB + b] = h;
  }
}

// ---------------- kernel 4: BN2 stats ----------------
__global__ void k4_bn2(const float* __restrict__ hT, const float* __restrict__ g,
                       const float* __restrict__ bta, float* __restrict__ ws) {
  __shared__ float redS[256], redQ[256];
  int j = blockIdx.x, tid = threadIdx.x;
  const float* row = hT + (size_t)j * BB;
  float s = 0, q = 0;
  for (int i = tid; i < BB; i += 256) { float v = row[i]; s += v; q = fmaf(v, v, q); }
  redS[tid] = s; redQ[tid] = q;
  __syncthreads();
  for (int k = 128; k > 0; k >>= 1) {
    if (tid < k) { redS[tid] += redS[tid + k]; redQ[tid] += redQ[tid + k]; }
    __syncthreads();
  }
  if (tid == 0) {
    float N = (float)BB;
    float mean = redS[0] / N;
    float var = redQ[0] / N - mean * mean;
    float sc = g[j] / sqrtf(var + EPSF);
    ws[64 + j] = sc;
    ws[96 + j] = bta[j] - mean * sc;
  }
}

// ---------------- kernel 5: BN2 apply + sigmoid + classifier ----------------
__global__ void k5_out(const float* __restrict__ hT, const float* __restrict__ ws,
                       const float* __restrict__ clsw, const float* __restrict__ clsb,
                       float* __restrict__ out) {
  __shared__ float hs[CC * 257];
  int b0 = blockIdx.x * 256, tid = threadIdx.x;
  for (int i = tid; i < CC * 256; i += 256) {
    int j = i >> 8, bb = i & 255;
    float v = fmaf(hT[(size_t)j * BB + b0 + bb], ws[64 + j], ws[96 + j]);
    hs[j * 257 + bb] = 1.f / (1.f + expf(-v));
  }
  __syncthreads();
  float o0 = clsb[0], o1 = clsb[1], o2 = clsb[2], o3 = clsb[3];
#pragma unroll
  for (int j = 0; j < CC; j++) {
    float h = hs[j * 257 + tid];
    o0 = fmaf(h, clsw[j * 4 + 0], o0);
    o1 = fmaf(h, clsw[j * 4 + 1], o1);
    o2 = fmaf(h, clsw[j * 4 + 2], o2);
    o3 = fmaf(h, clsw[j * 4 + 3], o3);
  }
  float4* out4 = reinterpret_cast<float4*>(out);
  out4[b0 + tid] = make_float4(o0, o1, o2, o3);
}

extern "C" void kernel_launch(void* const* d_in, const int* in_sizes, int n_in,
                              void* d_out, int out_size, void* d_ws, size_t ws_size,
                              hipStream_t stream) {
  const float* de   = (const float*)d_in[0];
  const float* dw   = (const float*)d_in[2];
  const float* db_  = (const float*)d_in[3];
  const float* pw   = (const float*)d_in[4];
  const float* pwb  = (const float*)d_in[5];
  const float* bn1g = (const float*)d_in[6];
  const float* bn1b = (const float*)d_in[7];
  const float* gcw  = (const float*)d_in[8];
  const float* fcw  = (const float*)d_in[9];
  const float* fcb  = (const float*)d_in[10];
  const float* bn2g = (const float*)d_in[11];
  const float* bn2b = (const float*)d_in[12];
  const float* clsw = (const float*)d_in[13];
  const float* clsb = (const float*)d_in[14];

  float* ws = (float*)d_ws;
  unsigned short* gcf = (unsigned short*)(ws + 128);
  float* hT   = ws + 4224;
  float* part = ws + 135296;
  unsigned int* x2h = (unsigned int*)(ws + 397440);
  float* out  = (float*)d_out;

  size_t need = ((size_t)397440 + 33554432ull) * 4ull;  // ~135.8 MB
  int useWs = (ws_size >= need) ? 1 : 0;

  k1_stats<<<BB, 256, 0, stream>>>(de, dw, db_, pw, pwb, part, x2h, useWs);
  k2_bn1<<<CC, 256, 0, stream>>>(part, bn1g, bn1b, ws, gcw, gcf);
  k3_main<<<BB, 256, 0, stream>>>(de, dw, db_, pw, pwb, ws, gcf, fcw, fcb, hT, x2h, useWs);
  k4_bn2<<<CC, 256, 0, stream>>>(hT, bn2g, bn2b, ws);
  k5_out<<<BB / 256, 256, 0, stream>>>(hT, ws, clsw, clsb, out);
}